// Round 2
// baseline (1194.923 us; speedup 1.0000x reference)
//
#include <hip/hip_runtime.h>

#define BB 16
#define C_INN 64
#define C_OUTT 64
#define V_INN 40962
#define V_OUTT 163842

constexpr int R_TOTAL = BB * C_OUTT;      // 1024 output rows (b,o) = r

// ---------------- Pass 1: Yt[u][r] = sum_c W[o][c]*x[b][c][u] + bias[o] -----
// r = b*64 + o. TRANSPOSED intermediate: per input vertex u, its 1024 row
// values are contiguous (4 KB). grid: (ceil(V_IN/256), B), block 256.
__global__ __launch_bounds__(256) void pass1_gemm_t(
    const float* __restrict__ x, const float* __restrict__ W,
    const float* __restrict__ bias, float* __restrict__ Yt)
{
    __shared__ float sW[C_OUTT * C_INN];   // 16 KB, [o][c]
    __shared__ float sB[C_OUTT];
    const int t = threadIdx.x;

    for (int i = t; i < C_OUTT * C_INN / 4; i += 256)
        ((float4*)sW)[i] = ((const float4*)W)[i];
    if (t < C_OUTT) sB[t] = bias[t];
    __syncthreads();

    int u = blockIdx.x * 256 + t;
    const int b = blockIdx.y;
    const bool valid = (u < V_INN);
    if (!valid) u = V_INN - 1;  // clamp so speculative loads stay in-bounds

    // x column for this u: 64 loads, each coalesced across the wave
    float xv[C_INN];
    const float* xp = x + (size_t)b * C_INN * V_INN + u;
    #pragma unroll
    for (int c = 0; c < C_INN; ++c) xv[c] = xp[(size_t)c * V_INN];

    // Write 64 outputs as 16 float4s at Yt[u*1024 + b*64 .. +63]:
    // per-lane 256 B contiguous region -> fully-dirty lines, L2 write-combines.
    float4* yp = (float4*)(Yt + (size_t)u * R_TOTAL + b * C_OUTT);
    #pragma unroll
    for (int o4 = 0; o4 < C_OUTT / 4; ++o4) {
        float accj[4];
        #pragma unroll
        for (int j = 0; j < 4; ++j) {
            const int o = 4 * o4 + j;
            float acc = sB[o];
            const float4* wrow = (const float4*)(sW + o * C_INN);  // wave-uniform -> LDS broadcast
            #pragma unroll
            for (int c4 = 0; c4 < C_INN / 4; ++c4) {
                float4 w = wrow[c4];
                acc = fmaf(w.x, xv[4 * c4 + 0], acc);
                acc = fmaf(w.y, xv[4 * c4 + 1], acc);
                acc = fmaf(w.z, xv[4 * c4 + 2], acc);
                acc = fmaf(w.w, xv[4 * c4 + 3], acc);
            }
            accj[j] = acc;
        }
        if (valid) {
            float4 v4; v4.x = accj[0]; v4.y = accj[1]; v4.z = accj[2]; v4.w = accj[3];
            yp[o4] = v4;
        }
    }
}

// ---------------- Pass 2: out[r][v] = 0.5*(Yt[i0[v]][r] + Yt[i1[v]][r]) -----
// Lane owns (v = v0 + lane, 64-row slab r0..r0+63). Gathers are per-lane
// CONTIGUOUS 256 B segments (16 x float4, every fetched line fully used;
// Yt = 168 MB is Infinity-Cache-resident). Stores: for each row r, lanes
// hold 64 consecutive v -> 256 B coalesced store (non-temporal: write-once
// stream, keep it out of L2). No LDS needed.
// grid: (ceil(V_OUT/64), R_TOTAL/256), block 256 (4 waves = 4 row-slabs).
__global__ __launch_bounds__(256) void pass2_gather_t(
    const float* __restrict__ Yt, const int* __restrict__ idx,
    float* __restrict__ out)
{
    const int vl   = threadIdx.x & 63;
    const int rblk = threadIdx.x >> 6;                 // 0..3 (wave id)
    const int r0   = blockIdx.y * 256 + rblk * 64;     // this thread's 64 rows
    int v = blockIdx.x * 64 + vl;
    const bool valid = (v < V_OUTT);
    if (!valid) v = V_OUTT - 1;                        // clamp (idx read stays in-bounds)

    const int2 iv = ((const int2*)idx)[v];             // i0, i1 (8B coalesced)

    const float4* pa = (const float4*)(Yt + (size_t)iv.x * R_TOTAL + r0);
    const float4* pb = (const float4*)(Yt + (size_t)iv.y * R_TOTAL + r0);

    float4 avg[16];
    #pragma unroll
    for (int j = 0; j < 16; ++j) {
        float4 a = pa[j], b = pb[j];
        avg[j].x = 0.5f * (a.x + b.x);
        avg[j].y = 0.5f * (a.y + b.y);
        avg[j].z = 0.5f * (a.z + b.z);
        avg[j].w = 0.5f * (a.w + b.w);
    }

    if (valid) {
        float* op = out + (size_t)r0 * V_OUTT + v;
        #pragma unroll
        for (int j = 0; j < 16; ++j) {                 // rows r0+4j .. r0+4j+3
            __builtin_nontemporal_store(avg[j].x, op + (size_t)(4 * j + 0) * V_OUTT);
            __builtin_nontemporal_store(avg[j].y, op + (size_t)(4 * j + 1) * V_OUTT);
            __builtin_nontemporal_store(avg[j].z, op + (size_t)(4 * j + 2) * V_OUTT);
            __builtin_nontemporal_store(avg[j].w, op + (size_t)(4 * j + 3) * V_OUTT);
        }
    }
}

// ---------------- Fallback (only if ws too small): fused gather+matvec -------
__global__ __launch_bounds__(256) void fused_fallback(
    const float* __restrict__ x, const int* __restrict__ idx,
    const float* __restrict__ W, const float* __restrict__ bias,
    float* __restrict__ out)
{
    __shared__ float sW[C_OUTT * C_INN];
    __shared__ float sB[C_OUTT];
    const int t = threadIdx.x;
    for (int i = t; i < C_OUTT * C_INN / 4; i += 256)
        ((float4*)sW)[i] = ((const float4*)W)[i];
    if (t < C_OUTT) sB[t] = bias[t];
    __syncthreads();

    int v = blockIdx.x * 256 + t;
    const int b = blockIdx.y;
    const bool valid = (v < V_OUTT);
    if (!valid) v = V_OUTT - 1;
    const int i0 = idx[2 * v], i1 = idx[2 * v + 1];

    float xv[C_INN];
    const float* xb = x + (size_t)b * C_INN * V_INN;
    #pragma unroll
    for (int c = 0; c < C_INN; ++c)
        xv[c] = 0.5f * (xb[(size_t)c * V_INN + i0] + xb[(size_t)c * V_INN + i1]);

    float* op = out + (size_t)b * C_OUTT * V_OUTT + v;
    for (int o = 0; o < C_OUTT; ++o) {
        float acc = sB[o];
        const float4* wrow = (const float4*)(sW + o * C_INN);
        #pragma unroll
        for (int c4 = 0; c4 < C_INN / 4; ++c4) {
            float4 w = wrow[c4];
            acc = fmaf(w.x, xv[4 * c4 + 0], acc);
            acc = fmaf(w.y, xv[4 * c4 + 1], acc);
            acc = fmaf(w.z, xv[4 * c4 + 2], acc);
            acc = fmaf(w.w, xv[4 * c4 + 3], acc);
        }
        if (valid) op[(size_t)o * V_OUTT] = acc;
    }
}

extern "C" void kernel_launch(void* const* d_in, const int* in_sizes, int n_in,
                              void* d_out, int out_size, void* d_ws, size_t ws_size,
                              hipStream_t stream) {
    const float* x    = (const float*)d_in[0];
    const int*   idx  = (const int*)d_in[1];   // harness delivers integer inputs as int32
    const float* W    = (const float*)d_in[2];
    const float* bias = (const float*)d_in[3];
    float* out = (float*)d_out;

    const size_t y_bytes = (size_t)BB * C_OUTT * V_INN * sizeof(float);  // 167.8 MB

    if (ws_size >= y_bytes) {
        float* Yt = (float*)d_ws;
        dim3 g1((V_INN + 255) / 256, BB);
        pass1_gemm_t<<<g1, 256, 0, stream>>>(x, W, bias, Yt);
        dim3 g2((V_OUTT + 63) / 64, R_TOTAL / 256);
        pass2_gather_t<<<g2, 256, 0, stream>>>(Yt, idx, out);
    } else {
        dim3 g((V_OUTT + 255) / 256, BB);
        fused_fallback<<<g, 256, 0, stream>>>(x, idx, W, bias, out);
    }
}